// Round 3
// baseline (298.861 us; speedup 1.0000x reference)
//
#include <hip/hip_runtime.h>

// Problem constants
#define B_ 32
#define N_ 8192
#define D_ 128
#define H_ 128
#define R_ (B_ * N_)   // 262144 rows total

#define TILES 2        // 64-row tiles per block
#define NBLK1 2048     // K1 grid: 128 rows per block, 64 blocks/batch

typedef _Float16 f16;
typedef __attribute__((ext_vector_type(4))) _Float16 f16x4;
typedef __attribute__((ext_vector_type(8))) _Float16 f16x8;
typedef __attribute__((ext_vector_type(4))) float f32x4;

// Workspace layout (bytes)
static constexpr size_t WPACK_OFF = 0;                       // 2*128*128 f16 = 64 KiB
static constexpr size_t VPART_OFF = 65536;                   // NBLK1*128 f32 = 1 MiB
static constexpr size_t SPART_OFF = VPART_OFF + (size_t)NBLK1 * 128 * 4;  // NBLK1 f32

__device__ __forceinline__ float silu_f(float v) {
    return v * __builtin_amdgcn_rcpf(1.0f + __expf(-v));
}

__device__ __forceinline__ f32x4 mfma16(f16x8 a, f16x8 b, f32x4 c) {
    return __builtin_amdgcn_mfma_f32_16x16x32_f16(a, b, c, 0, 0, 0);
}

// ---------------------------------------------------------------------------
// K0: prepack Wg1, Wn1 (fp32 row-major [k][n] 128x128) into fp16 MFMA
// fragment order: frag[(nt*4+kc)*64 + lane][j]
//   = W[(kc*32 + (lane>>4)*8 + j)][nt*16 + (lane&15)]
// (Wn2 no longer packed: it is applied post-pooling in K2, in fp32.)
// ---------------------------------------------------------------------------
__global__ void k0_prepack(const float* __restrict__ Wg1,
                           const float* __restrict__ Wn1,
                           f16* __restrict__ wp) {
    int tid = blockIdx.x * 256 + threadIdx.x;  // 0..32767
    int m    = tid >> 14;
    int r    = tid & 16383;
    int j    = r & 7;
    int lane = (r >> 3) & 63;
    int kc   = (r >> 9) & 3;
    int nt   = r >> 11;
    int k = kc * 32 + (lane >> 4) * 8 + j;
    int n = nt * 16 + (lane & 15);
    const float* W = m ? Wn1 : Wg1;
    wp[tid] = (f16)W[k * 128 + n];
}

// ---------------------------------------------------------------------------
// K1: gate + n1 only (n2 moved post-pooling into K2). 2048 blocks x 2 tiles
// of 64 rows. 256 threads = 4 waves; wave w owns col-stripes {2w, 2w+1}.
// Transposed MFMA (W as A): lane holds D[col = st*16+q*4+r][row = mt*16+c].
// Per tile: [stage x -> swizzled LDS; prefetch next tile's x] B
//   [gate1/n1 MFMAs -> an regs; h = silu(an+bn1) kept packed f16 in regs;
//    gate partial -> gpart] C [e = exp(gate); V += e*h; S += e]
// V,S accumulate in registers across tiles; one partial write per block.
// Weight fragments loaded once per block (was once per 64-row tile).
// ---------------------------------------------------------------------------
__global__ __launch_bounds__(256, 3) void k1_fused(
        const float* __restrict__ x,
        const float* __restrict__ bg1, const float* __restrict__ wg2,
        const float* __restrict__ bg2, const float* __restrict__ bn1,
        const f16* __restrict__ wp,
        float* __restrict__ vpart, float* __restrict__ spart) {
    __shared__ f16 xlds[64 * 128];
    __shared__ float gpart[4][64];

    const int tid  = threadIdx.x;
    const int w    = tid >> 6;    // wave id: stripes 2w, 2w+1
    const int lane = tid & 63;
    const int q    = lane >> 4;
    const int c    = lane & 15;

    // ---- issue tile-0 x loads first (8 float4 / thread, HBM latency) ----
    const long rowbase = (long)blockIdx.x * (64 * TILES);
    const float4* xg = (const float4*)x + rowbase * 32;
    float4 xv[8];
#pragma unroll
    for (int s = 0; s < 8; ++s) xv[s] = xg[s * 256 + tid];

    // ---- weight fragments (fg1, fn1), loaded once per block from L2 ----
    const f16x8* wpv = (const f16x8*)wp;
    f16x8 fg1[2][4], fn1[2][4];
#pragma unroll
    for (int s = 0; s < 2; ++s)
#pragma unroll
        for (int kc = 0; kc < 4; ++kc) {
            int base = ((2 * w + s) * 4 + kc) * 64 + lane;
            fg1[s][kc] = wpv[base];
            fn1[s][kc] = wpv[2048 + base];
        }
    float bg1q[2][4], wg2q[2][4], bn1q[2][4];
#pragma unroll
    for (int s = 0; s < 2; ++s)
#pragma unroll
        for (int r = 0; r < 4; ++r) {
            int col = (2 * w + s) * 16 + q * 4 + r;
            bg1q[s][r] = bg1[col];
            wg2q[s][r] = wg2[col];
            bn1q[s][r] = bn1[col];
        }
    const float bg2v = bg2[0];

    // Swizzled per-lane LDS read offsets (halves) for A-frag reads
    const int loh_e = (q * 16 + (c ^ q)) * 8;        // kc even
    const int loh_o = (q * 16 + (c ^ (q | 4))) * 8;  // kc odd

    float V[2][4] = {{0.f, 0.f, 0.f, 0.f}, {0.f, 0.f, 0.f, 0.f}};
    float Sacc = 0.f;

#pragma unroll
    for (int t = 0; t < TILES; ++t) {
        // ---- stage x tile into swizzled frag-order LDS (xv dies here) ----
#pragma unroll
        for (int s = 0; s < 8; ++s) {
            int e   = s * 256 + tid;      // 0..2047 float4s
            int row = e >> 5, c4 = e & 31;
            int mt = row >> 4, cc = row & 15;
            int kc = c4 >> 3, qq = (c4 >> 1) & 3, j = (c4 & 1) * 4;
            int sw = (c4 >> 1) & 7;       // = (kc&1)*4 + qq
            float4 vv = xv[s];
            f16x4 hv = {(f16)vv.x, (f16)vv.y, (f16)vv.z, (f16)vv.w};
            *(f16x4*)&xlds[((mt * 4 + kc) * 64 + qq * 16 + (cc ^ sw)) * 8 + j] = hv;
        }
        // ---- prefetch next tile: HBM latency hides under this tile's math ----
        if (t + 1 < TILES) {
#pragma unroll
            for (int s = 0; s < 8; ++s)
                xv[s] = xg[(t + 1) * 2048 + s * 256 + tid];
        }
        __syncthreads();  // B: xlds ready

        // ---- gate1 + n1: per mt, accumulate over kc for both stripes ----
        f16x4 hq[4][2];   // packed h = silu(n1) held across barrier C
#pragma unroll
        for (int mt = 0; mt < 4; ++mt) {
            f16x8 a[4];
#pragma unroll
            for (int kc = 0; kc < 4; ++kc)
                a[kc] = *(const f16x8*)&xlds[(mt * 4 + kc) * 512 +
                                             ((kc & 1) ? loh_o : loh_e)];
            f32x4 ag[2] = {{0.f,0.f,0.f,0.f},{0.f,0.f,0.f,0.f}};
            f32x4 an[2] = {{0.f,0.f,0.f,0.f},{0.f,0.f,0.f,0.f}};
#pragma unroll
            for (int kc = 0; kc < 4; ++kc) {
#pragma unroll
                for (int s = 0; s < 2; ++s) {
                    ag[s] = mfma16(fg1[s][kc], a[kc], ag[s]);
                    an[s] = mfma16(fn1[s][kc], a[kc], an[s]);
                }
            }
            // h kept in registers (was: written to h1lds for the n2 GEMM)
#pragma unroll
            for (int s = 0; s < 2; ++s) {
                f16x4 h4;
#pragma unroll
                for (int r = 0; r < 4; ++r) h4[r] = (f16)silu_f(an[s][r] + bn1q[s][r]);
                hq[mt][s] = h4;
            }
            // gate partial over this wave's 32 cols
            float p = 0.f;
#pragma unroll
            for (int s = 0; s < 2; ++s)
#pragma unroll
                for (int r = 0; r < 4; ++r)
                    p += silu_f(ag[s][r] + bg1q[s][r]) * wg2q[s][r];
            p += __shfl_xor(p, 16);
            p += __shfl_xor(p, 32);
            if (lane < 16) gpart[w][mt * 16 + lane] = p;
        }
        __syncthreads();  // C: gpart ready, xlds consumed

        // ---- finalize gate scores; weighted accumulate into V, S ----
#pragma unroll
        for (int mt = 0; mt < 4; ++mt) {
            float g = bg2v + gpart[0][mt * 16 + c] + gpart[1][mt * 16 + c]
                           + gpart[2][mt * 16 + c] + gpart[3][mt * 16 + c];
            float e4 = __expf(g);
            Sacc += e4;
#pragma unroll
            for (int s = 0; s < 2; ++s)
#pragma unroll
                for (int r = 0; r < 4; ++r)
                    V[s][r] += e4 * (float)hq[mt][s][r];
        }
    }

    // ---- reduce over rows held by different c-lanes; write partials ----
#pragma unroll
    for (int m = 1; m < 16; m <<= 1)
#pragma unroll
        for (int s = 0; s < 2; ++s)
#pragma unroll
            for (int r = 0; r < 4; ++r) V[s][r] += __shfl_xor(V[s][r], m);
    if (c == 0) {
#pragma unroll
        for (int s = 0; s < 2; ++s) {
            float4 o = {V[s][0], V[s][1], V[s][2], V[s][3]};
            *(float4*)&vpart[(long)blockIdx.x * 128 + (2 * w + s) * 16 + q * 4] = o;
        }
    }
    if (w == 0) {
#pragma unroll
        for (int m = 1; m < 16; m <<= 1) Sacc += __shfl_xor(Sacc, m);
        if (lane == 0) spart[blockIdx.x] = Sacc;
    }
}

// ---------------------------------------------------------------------------
// K2: combine per-block partials, then apply the pooled n2 linear layer:
//   out[b] = (sum_k vpart[b,k] / S_b) @ Wn2 + bn2      (Sigma attn = 1)
// 32 blocks (one per batch) x 256 threads. 64 partials per batch.
// ---------------------------------------------------------------------------
__global__ void k2_combine(const float* __restrict__ vpart,
                           const float* __restrict__ spart,
                           const float* __restrict__ Wn2,
                           const float* __restrict__ bn2,
                           float* __restrict__ out) {
    const int b = blockIdx.x;
    const int t = threadIdx.x;   // 0..255

    __shared__ float pooled[128];
    __shared__ float sred;

    // V partial sum: threads 0..127 each own one output column
    float v = 0.f;
    if (t < 128) {
        const float* vp = vpart + (long)b * 64 * 128;
#pragma unroll 8
        for (int k = 0; k < 64; ++k) v += vp[k * 128 + t];
    }

    // Denominator: all threads execute (proven round-0 pattern, no divergent
    // shfl). Wave 0 lanes hold the 64 spart entries of this batch.
    float s = (t < 64) ? spart[b * 64 + t] : 0.f;
#pragma unroll
    for (int m = 1; m < 64; m <<= 1) s += __shfl_xor(s, m);
    if (t == 0) sred = s;

    __syncthreads();
    if (t < 128) pooled[t] = v / sred;
    __syncthreads();
    if (t < 128) {
        float acc = bn2[t];
#pragma unroll 8
        for (int k = 0; k < 128; ++k) acc += pooled[k] * Wn2[k * 128 + t];
        out[b * 128 + t] = acc;
    }
}

// ---------------------------------------------------------------------------
extern "C" void kernel_launch(void* const* d_in, const int* in_sizes, int n_in,
                              void* d_out, int out_size, void* d_ws, size_t ws_size,
                              hipStream_t stream) {
    const float* x   = (const float*)d_in[0];
    const float* Wg1 = (const float*)d_in[1];
    const float* bg1 = (const float*)d_in[2];
    const float* Wg2 = (const float*)d_in[3];
    const float* bg2 = (const float*)d_in[4];
    const float* Wn1 = (const float*)d_in[5];
    const float* bn1 = (const float*)d_in[6];
    const float* Wn2 = (const float*)d_in[7];
    const float* bn2 = (const float*)d_in[8];
    float* out = (float*)d_out;

    char* ws = (char*)d_ws;
    f16*   wp    = (f16*)(ws + WPACK_OFF);
    float* vpart = (float*)(ws + VPART_OFF);
    float* spart = (float*)(ws + SPART_OFF);

    k0_prepack<<<128, 256, 0, stream>>>(Wg1, Wn1, wp);
    k1_fused<<<NBLK1, 256, 0, stream>>>(x, bg1, Wg2, bg2, bn1, wp, vpart, spart);
    k2_combine<<<32, 256, 0, stream>>>(vpart, spart, Wn2, bn2, out);
}

// Round 4
// 218.127 us; speedup vs baseline: 1.3701x; 1.3701x over previous
//
#include <hip/hip_runtime.h>

// Problem constants
#define B_ 32
#define N_ 8192
#define D_ 128
#define H_ 128
#define R_ (B_ * N_)   // 262144 rows total

#define NBLK 4096      // K1 grid: one 64-row tile per block, 128 blocks/batch

typedef _Float16 f16;
typedef __attribute__((ext_vector_type(4))) _Float16 f16x4;
typedef __attribute__((ext_vector_type(8))) _Float16 f16x8;
typedef __attribute__((ext_vector_type(4))) float f32x4;

// Workspace layout (bytes)
static constexpr size_t WPACK_OFF = 0;                       // 2*128*128 f16 = 64 KiB
static constexpr size_t VPART_OFF = 65536;                   // NBLK*128 f32 = 2 MiB
static constexpr size_t SPART_OFF = VPART_OFF + (size_t)NBLK * 128 * 4;  // NBLK f32

__device__ __forceinline__ float silu_f(float v) {
    return v * __builtin_amdgcn_rcpf(1.0f + __expf(-v));
}

__device__ __forceinline__ f32x4 mfma16(f16x8 a, f16x8 b, f32x4 c) {
    return __builtin_amdgcn_mfma_f32_16x16x32_f16(a, b, c, 0, 0, 0);
}

// ---------------------------------------------------------------------------
// K0: prepack Wg1, Wn1 (fp32 row-major [k][n] 128x128) into fp16 MFMA
// fragment order: frag[(nt*4+kc)*64 + lane][j]
//   = W[(kc*32 + (lane>>4)*8 + j)][nt*16 + (lane&15)]
// (Wn2 not packed: applied post-pooling in K2, in fp32.)
// ---------------------------------------------------------------------------
__global__ void k0_prepack(const float* __restrict__ Wg1,
                           const float* __restrict__ Wn1,
                           f16* __restrict__ wp) {
    int tid = blockIdx.x * 256 + threadIdx.x;  // 0..32767
    int m    = tid >> 14;
    int r    = tid & 16383;
    int j    = r & 7;
    int lane = (r >> 3) & 63;
    int kc   = (r >> 9) & 3;
    int nt   = r >> 11;
    int k = kc * 32 + (lane >> 4) * 8 + j;
    int n = nt * 16 + (lane & 15);
    const float* W = m ? Wn1 : Wg1;
    wp[tid] = (f16)W[k * 128 + n];
}

// ---------------------------------------------------------------------------
// K1: round-0 proven single-tile structure + n2 hoisted out (applied
// post-pooling in K2, valid because softmax weights sum to 1).
// One 64-row tile per block; 256 threads = 4 waves; wave w owns col-stripes
// {2w, 2w+1}. Transposed MFMA (W as A): lane holds
// D[col = st*16+q*4+r][row = mt*16+c].
// Register discipline (peak live ~150 < 168 cap, no spill):
//   xv[8] (32 regs) DIES at staging, before hq/V exist;
//   fg1+fn1 (64) resident through the MFMA phase;
//   hq (16, packed f16) replaces the old h1lds round-trip AND the old
//   fn2 fragments (32) — net -16 vs round-0.
// Phases: [load x + fg1/fn1 + biases; stage x] B [gate1/n1 MFMAs; hq regs;
//   gate partials -> gpart] C [e=exp(gate); V = sum e*hq; S = sum e;
//   reduce + write partials]
// ---------------------------------------------------------------------------
__global__ __launch_bounds__(256, 3) void k1_fused(
        const float* __restrict__ x,
        const float* __restrict__ bg1, const float* __restrict__ wg2,
        const float* __restrict__ bg2, const float* __restrict__ bn1,
        const f16* __restrict__ wp,
        float* __restrict__ vpart, float* __restrict__ spart) {
    __shared__ f16 xlds[64 * 128];
    __shared__ float gpart[4][64];

    const int tid  = threadIdx.x;
    const int w    = tid >> 6;    // wave id: stripes 2w, 2w+1
    const int lane = tid & 63;
    const int q    = lane >> 4;
    const int c    = lane & 15;

    // ---- issue x tile loads first (8 float4 / thread) ----
    const long rowbase = (long)blockIdx.x * 64;
    const float4* xg = (const float4*)x + rowbase * 32;
    float4 xv[8];
#pragma unroll
    for (int s = 0; s < 8; ++s) xv[s] = xg[s * 256 + tid];

    // ---- weight fragments (fg1, fn1) ----
    const f16x8* wpv = (const f16x8*)wp;
    f16x8 fg1[2][4], fn1[2][4];
#pragma unroll
    for (int s = 0; s < 2; ++s)
#pragma unroll
        for (int kc = 0; kc < 4; ++kc) {
            int base = ((2 * w + s) * 4 + kc) * 64 + lane;
            fg1[s][kc] = wpv[base];
            fn1[s][kc] = wpv[2048 + base];
        }
    float bg1q[2][4], wg2q[2][4], bn1q[2][4];
#pragma unroll
    for (int s = 0; s < 2; ++s)
#pragma unroll
        for (int r = 0; r < 4; ++r) {
            int col = (2 * w + s) * 16 + q * 4 + r;
            bg1q[s][r] = bg1[col];
            wg2q[s][r] = wg2[col];
            bn1q[s][r] = bn1[col];
        }
    const float bg2v = bg2[0];

    // Swizzled per-lane LDS read offsets (halves) for A-frag reads
    const int loh_e = (q * 16 + (c ^ q)) * 8;        // kc even
    const int loh_o = (q * 16 + (c ^ (q | 4))) * 8;  // kc odd

    // ---- stage x tile into swizzled frag-order LDS (xv dies here) ----
#pragma unroll
    for (int s = 0; s < 8; ++s) {
        int e   = s * 256 + tid;      // 0..2047 float4s
        int row = e >> 5, c4 = e & 31;
        int mt = row >> 4, cc = row & 15;
        int kc = c4 >> 3, qq = (c4 >> 1) & 3, j = (c4 & 1) * 4;
        int sw = (c4 >> 1) & 7;       // = (kc&1)*4 + qq
        float4 vv = xv[s];
        f16x4 hv = {(f16)vv.x, (f16)vv.y, (f16)vv.z, (f16)vv.w};
        *(f16x4*)&xlds[((mt * 4 + kc) * 64 + qq * 16 + (cc ^ sw)) * 8 + j] = hv;
    }
    __syncthreads();  // B: xlds ready

    // ---- gate1 + n1: per mt, accumulate over kc for both stripes ----
    f16x4 hq[4][2];   // packed h = silu(n1) held across barrier C
#pragma unroll
    for (int mt = 0; mt < 4; ++mt) {
        f16x8 a[4];
#pragma unroll
        for (int kc = 0; kc < 4; ++kc)
            a[kc] = *(const f16x8*)&xlds[(mt * 4 + kc) * 512 +
                                         ((kc & 1) ? loh_o : loh_e)];
        f32x4 ag[2] = {{0.f,0.f,0.f,0.f},{0.f,0.f,0.f,0.f}};
        f32x4 an[2] = {{0.f,0.f,0.f,0.f},{0.f,0.f,0.f,0.f}};
#pragma unroll
        for (int kc = 0; kc < 4; ++kc) {
#pragma unroll
            for (int s = 0; s < 2; ++s) {
                ag[s] = mfma16(fg1[s][kc], a[kc], ag[s]);
                an[s] = mfma16(fn1[s][kc], a[kc], an[s]);
            }
        }
        // h kept packed in registers (was: h1lds round-trip + n2 GEMM)
#pragma unroll
        for (int s = 0; s < 2; ++s) {
            f16x4 h4;
#pragma unroll
            for (int r = 0; r < 4; ++r) h4[r] = (f16)silu_f(an[s][r] + bn1q[s][r]);
            hq[mt][s] = h4;
        }
        // gate partial over this wave's 32 cols
        float p = 0.f;
#pragma unroll
        for (int s = 0; s < 2; ++s)
#pragma unroll
            for (int r = 0; r < 4; ++r)
                p += silu_f(ag[s][r] + bg1q[s][r]) * wg2q[s][r];
        p += __shfl_xor(p, 16);
        p += __shfl_xor(p, 32);
        if (lane < 16) gpart[w][mt * 16 + lane] = p;
    }
    __syncthreads();  // C: gpart ready

    // ---- finalize gate scores (redundant per wave): e for rows mt*16+c ----
    float e4[4];
#pragma unroll
    for (int mt = 0; mt < 4; ++mt) {
        float g = bg2v + gpart[0][mt * 16 + c] + gpart[1][mt * 16 + c]
                       + gpart[2][mt * 16 + c] + gpart[3][mt * 16 + c];
        e4[mt] = __expf(g);
    }

    // ---- weighted accumulation: V[s][r] = sum_mt e4[mt] * h ----
    float V[2][4] = {{0.f,0.f,0.f,0.f},{0.f,0.f,0.f,0.f}};
#pragma unroll
    for (int mt = 0; mt < 4; ++mt)
#pragma unroll
        for (int s = 0; s < 2; ++s)
#pragma unroll
            for (int r = 0; r < 4; ++r)
                V[s][r] += e4[mt] * (float)hq[mt][s][r];

    // ---- reduce over rows held by different c-lanes; write partials ----
#pragma unroll
    for (int m = 1; m < 16; m <<= 1)
#pragma unroll
        for (int s = 0; s < 2; ++s)
#pragma unroll
            for (int r = 0; r < 4; ++r) V[s][r] += __shfl_xor(V[s][r], m);
    if (c == 0) {
#pragma unroll
        for (int s = 0; s < 2; ++s) {
            float4 o = {V[s][0], V[s][1], V[s][2], V[s][3]};
            *(float4*)&vpart[(long)blockIdx.x * 128 + (2 * w + s) * 16 + q * 4] = o;
        }
    }
    if (w == 0) {
        float Sl = e4[0] + e4[1] + e4[2] + e4[3];  // rows mt*16+c (q duplicates)
#pragma unroll
        for (int m = 1; m < 16; m <<= 1) Sl += __shfl_xor(Sl, m);
        if (lane == 0) spart[blockIdx.x] = Sl;
    }
}

// ---------------------------------------------------------------------------
// K2: combine per-block partials, then apply the pooled n2 linear layer:
//   out[b] = (sum_k vpart[b,k] / S_b) @ Wn2 + bn2      (Sigma attn = 1)
// 32 blocks (one per batch) x 256 threads. 128 partials per batch.
// ---------------------------------------------------------------------------
__global__ void k2_combine(const float* __restrict__ vpart,
                           const float* __restrict__ spart,
                           const float* __restrict__ Wn2,
                           const float* __restrict__ bn2,
                           float* __restrict__ out) {
    const int b = blockIdx.x;
    const int t = threadIdx.x;   // 0..255

    __shared__ float pooled[128];
    __shared__ float sred2[2];

    // V partial sum: threads 0..127 each own one output column
    float v = 0.f;
    if (t < 128) {
        const float* vp = vpart + (long)b * 128 * 128;
#pragma unroll 8
        for (int k = 0; k < 128; ++k) v += vp[k * 128 + t];
    }

    // Denominator: threads 0..127 (waves 0,1) hold one spart each;
    // unconditional full-wave shuffles (no divergent shfl).
    float s = (t < 128) ? spart[b * 128 + t] : 0.f;
#pragma unroll
    for (int m = 1; m < 64; m <<= 1) s += __shfl_xor(s, m);
    if (t < 128 && (t & 63) == 0) sred2[t >> 6] = s;
    __syncthreads();

    if (t < 128) pooled[t] = v / (sred2[0] + sred2[1]);
    __syncthreads();
    if (t < 128) {
        float acc = bn2[t];
#pragma unroll 8
        for (int k = 0; k < 128; ++k) acc += pooled[k] * Wn2[k * 128 + t];
        out[b * 128 + t] = acc;
    }
}

// ---------------------------------------------------------------------------
extern "C" void kernel_launch(void* const* d_in, const int* in_sizes, int n_in,
                              void* d_out, int out_size, void* d_ws, size_t ws_size,
                              hipStream_t stream) {
    const float* x   = (const float*)d_in[0];
    const float* Wg1 = (const float*)d_in[1];
    const float* bg1 = (const float*)d_in[2];
    const float* Wg2 = (const float*)d_in[3];
    const float* bg2 = (const float*)d_in[4];
    const float* Wn1 = (const float*)d_in[5];
    const float* bn1 = (const float*)d_in[6];
    const float* Wn2 = (const float*)d_in[7];
    const float* bn2 = (const float*)d_in[8];
    float* out = (float*)d_out;

    char* ws = (char*)d_ws;
    f16*   wp    = (f16*)(ws + WPACK_OFF);
    float* vpart = (float*)(ws + VPART_OFF);
    float* spart = (float*)(ws + SPART_OFF);

    k0_prepack<<<128, 256, 0, stream>>>(Wg1, Wn1, wp);
    k1_fused<<<NBLK, 256, 0, stream>>>(x, bg1, Wg2, bg2, bn1, wp, vpart, spart);
    k2_combine<<<32, 256, 0, stream>>>(vpart, spart, Wn2, bn2, out);
}